// Round 1
// baseline (909.847 us; speedup 1.0000x reference)
//
#include <hip/hip_runtime.h>
#include <hip/hip_bf16.h>

#define IN_CH 16
#define OUT_CH 16
#define HID 32

// ---------------------------------------------------------------------------
// Kernel A: feat_sum[i] = sum over edges of features[col[e]][i]   (16 floats)
// ---------------------------------------------------------------------------
__global__ __launch_bounds__(256) void k_featsum(
    const float* __restrict__ feat, const int* __restrict__ col, int E,
    float* __restrict__ fs) {
  float s[IN_CH];
#pragma unroll
  for (int i = 0; i < IN_CH; ++i) s[i] = 0.f;

  for (int e = blockIdx.x * blockDim.x + threadIdx.x; e < E;
       e += gridDim.x * blockDim.x) {
    int c = col[e];
    const float4* fp = reinterpret_cast<const float4*>(feat + (size_t)c * IN_CH);
    float4 a = fp[0], b = fp[1], cc = fp[2], d = fp[3];
    s[0] += a.x;  s[1] += a.y;  s[2] += a.z;  s[3] += a.w;
    s[4] += b.x;  s[5] += b.y;  s[6] += b.z;  s[7] += b.w;
    s[8] += cc.x; s[9] += cc.y; s[10] += cc.z; s[11] += cc.w;
    s[12] += d.x; s[13] += d.y; s[14] += d.z; s[15] += d.w;
  }

  // wave(64)-level butterfly reduce, then one atomic per wave per component
#pragma unroll
  for (int i = 0; i < IN_CH; ++i) {
    float v = s[i];
#pragma unroll
    for (int off = 32; off > 0; off >>= 1) v += __shfl_down(v, off);
    if ((threadIdx.x & 63) == 0) atomicAdd(&fs[i], v);
  }
}

// ---------------------------------------------------------------------------
// Kernel B: Wce[k][o] = sum_i wc[k][o*16+i] * fs[i]   (32x16)
//           bce[o]    = sum_i bc[o*16+i]    * fs[i]   (16)
// One block of 512 threads.
// ---------------------------------------------------------------------------
__global__ __launch_bounds__(512) void k_wce(
    const float* __restrict__ wc, const float* __restrict__ bc,
    const float* __restrict__ fs, float* __restrict__ wce,
    float* __restrict__ bce) {
  __shared__ float sfs[IN_CH];
  if (threadIdx.x < IN_CH) sfs[threadIdx.x] = fs[threadIdx.x];
  __syncthreads();

  int t = threadIdx.x;            // t = k*16 + o, t < 512
  int k = t >> 4, o = t & 15;
  float acc = 0.f;
#pragma unroll
  for (int i = 0; i < IN_CH; ++i)
    acc += wc[k * (IN_CH * OUT_CH) + o * IN_CH + i] * sfs[i];
  wce[t] = acc;

  if (t < OUT_CH) {
    float a = 0.f;
#pragma unroll
    for (int i = 0; i < IN_CH; ++i) a += bc[t * IN_CH + i] * sfs[i];
    bce[t] = a;
  }
}

// ---------------------------------------------------------------------------
// Kernel C: per-edge MLP + scatter-add.
// Weight accesses are wave-uniform with compile-time offsets -> s_load/SGPR,
// so the VALU pipe runs pure v_fmac_f32 (v, s, v).
// ---------------------------------------------------------------------------
__device__ __forceinline__ float silu(float x) {
  return x * __frcp_rn(1.f + __expf(-x));
}

__global__ __launch_bounds__(256) void k_edges(
    const float* __restrict__ coords, const int* __restrict__ row,
    const int* __restrict__ col, int E,
    const float* __restrict__ w1, const float* __restrict__ b1,
    const float* __restrict__ w2, const float* __restrict__ b2,
    const float* __restrict__ wce, const float* __restrict__ bce,
    float* __restrict__ out) {
  int e = blockIdx.x * blockDim.x + threadIdx.x;
  if (e >= E) return;

  int r = row[e];
  int c = col[e];

  float rx = coords[r * 3 + 0] - coords[c * 3 + 0];
  float ry = coords[r * 3 + 1] - coords[c * 3 + 1];
  float rz = coords[r * 3 + 2] - coords[c * 3 + 2];
  float d = sqrtf(rx * rx + ry * ry + rz * rz);

  float h1[HID];
#pragma unroll
  for (int j = 0; j < HID; ++j) {
    float x = d * w1[j] + b1[j];
    h1[j] = silu(x);
  }

  float h2[HID];
#pragma unroll
  for (int j = 0; j < HID; ++j) h2[j] = b2[j];
#pragma unroll
  for (int k = 0; k < HID; ++k) {
    float hk = h1[k];
#pragma unroll
    for (int j = 0; j < HID; ++j) h2[j] += hk * w2[k * HID + j];
  }
#pragma unroll
  for (int j = 0; j < HID; ++j) h2[j] = silu(h2[j]);

  float m[OUT_CH];
#pragma unroll
  for (int o = 0; o < OUT_CH; ++o) m[o] = bce[o];
#pragma unroll
  for (int k = 0; k < HID; ++k) {
    float hk = h2[k];
#pragma unroll
    for (int o = 0; o < OUT_CH; ++o) m[o] += hk * wce[k * OUT_CH + o];
  }

  float* op = out + (size_t)r * OUT_CH;
#pragma unroll
  for (int o = 0; o < OUT_CH; ++o) atomicAdd(op + o, m[o]);
}

// ---------------------------------------------------------------------------
// launch
// ---------------------------------------------------------------------------
extern "C" void kernel_launch(void* const* d_in, const int* in_sizes, int n_in,
                              void* d_out, int out_size, void* d_ws,
                              size_t ws_size, hipStream_t stream) {
  const float* features = (const float*)d_in[0];
  const float* coords   = (const float*)d_in[1];
  const int*   eidx     = (const int*)d_in[2];
  const float* w1       = (const float*)d_in[3];
  const float* b1       = (const float*)d_in[4];
  const float* w2       = (const float*)d_in[5];
  const float* b2       = (const float*)d_in[6];
  const float* wc       = (const float*)d_in[7];
  const float* bc       = (const float*)d_in[8];

  const int E = in_sizes[2] / 2;
  const int* row = eidx;
  const int* col = eidx + E;

  float* fs  = (float*)d_ws;        // 16 floats
  float* wce = fs + 16;             // 512 floats
  float* bce = wce + 512;           // 16 floats

  float* out = (float*)d_out;

  // zero feat_sum accumulator and the output (we accumulate atomically)
  hipMemsetAsync(fs, 0, IN_CH * sizeof(float), stream);
  hipMemsetAsync(out, 0, (size_t)out_size * sizeof(float), stream);

  k_featsum<<<256, 256, 0, stream>>>(features, col, E, fs);
  k_wce<<<1, 512, 0, stream>>>(wc, bc, fs, wce, bce);

  int blocks = (E + 255) / 256;
  k_edges<<<blocks, 256, 0, stream>>>(coords, row, col, E, w1, b1, w2, b2,
                                      wce, bce, out);
}